// Round 10
// baseline (124.716 us; speedup 1.0000x reference)
//
#include <hip/hip_runtime.h>
#include <hip/hip_bf16.h>
#include <math.h>

// NTXent loss, N=8192 rows, D=128.
// loss = mean_i [ log(sum_{j!=i} exp(2*cos_ij)) - 2*cos_{i,partner} ]
// R18: R17 (spill-free full-matrix) shows per-work cost identical to the
// triangle version: sim time scales with chunk-phases, ~8x pipe-work, and
// survived removal of atomics/spill/colsum/occupancy changes. Diagnosis:
// the lockstep LDS-staging phase structure itself -- per chunk, ds_read
// latency + MFMA chain + 2 block barriers pin all 4 waves to the same
// critical path; nothing pipelines across a phase. R18 removes shared
// state entirely: B streams L2->registers in 32-col chunks via a named
// 2-deep double buffer (bA/bB, static idx, rule #20); no LDS, no barriers,
// no glds, no asm. Each wave autonomous: 32-row strip x 512-col group;
// block = 4 waves sharing the same col group (L1 reuse of the B stream).
// De-swizzled loads read exactly the bytes the LDS path delivered (XOR
// cancels). B redundancy: 512 MB L2 ~15us worst case -- throughput-bound,
// the regime wave overlap hides. 1024 blocks, ~125 VGPR, LDS 0 -> 4/CU.

typedef __attribute__((ext_vector_type(8))) short bf16x8;   // 8 bf16 = 4 VGPRs
typedef __attribute__((ext_vector_type(4))) float f32x4;

#define NROWS 8192
#define DDIM  128
#define BHALF 4096
#define NCG   16                    // col groups
#define CGSZ  512                   // cols per group
#define NCHUNK 16                   // 16 chunks of 32 cols
// zn scaled by sqrt(2/ln2): acc = (2/ln2)*cos, exp(2cos) = exp2(acc)
#define SQRT_E2S 1.6986435980707531f
#define LN2      0.6931471805599453f
#define EXPDIAG  7.38905609893065f

static __device__ __forceinline__ unsigned short f2bf(float f) {
  unsigned int u = __float_as_uint(f);
  unsigned int r = (u + 0x7fffu + ((u >> 16) & 1u)) >> 16;   // RNE
  return (unsigned short)r;
}

// ---- Kernel 1: normalize (scaled) + fp32 pair-dots + zero out ------------
// Block b: waves 0,1 -> rows 2b,2b+1 (zi); waves 2,3 -> their partners (zj).
__global__ void norm_kernel(const float* __restrict__ zi, const float* __restrict__ zj,
                            unsigned short* __restrict__ zn,
                            float* __restrict__ pos, float* __restrict__ out) {
  __shared__ float2 xbuf[2][64];
  int wave = threadIdx.x >> 6;
  int lane = threadIdx.x & 63;
  int pi   = blockIdx.x * 2 + (wave & 1);           // pair index
  int row  = pi + (wave >> 1) * BHALF;
  const float* src = (row < BHALF) ? (zi + (size_t)row * DDIM)
                                   : (zj + (size_t)(row - BHALF) * DDIM);
  float2 v = *(const float2*)(src + 2 * lane);
  float ss = v.x * v.x + v.y * v.y;
  #pragma unroll
  for (int off = 1; off < 64; off <<= 1) ss += __shfl_xor(ss, off);
  float scale = SQRT_E2S / fmaxf(sqrtf(ss), 1e-8f);
  v.x *= scale; v.y *= scale;
  unsigned int lo = f2bf(v.x), hi = f2bf(v.y);
  ((unsigned int*)(zn + (size_t)row * DDIM))[lane] = lo | (hi << 16);

  if (wave >= 2) xbuf[wave - 2][lane] = v;
  __syncthreads();
  if (wave < 2) {                                    // d = (2/ln2)*cos(i, i+B)
    float2 w = xbuf[wave][lane];
    float d = v.x * w.x + v.y * w.y;
    #pragma unroll
    for (int off = 1; off < 64; off <<= 1) d += __shfl_xor(d, off);
    if (lane == 0) pos[pi] = d;
  }
  if (blockIdx.x == 0 && threadIdx.x == 0) out[0] = 0.0f;
}

// ---- Kernel 2: full-matrix sim + exp + row partial sums (barrier-free) ---
// 1024 blocks x 4 autonomous waves. Wave: strip = (bid>>4)*4 + w (32 rows),
// col group cg = bid&15 (512 cols, shared by the block's 4 waves for L1).
// B streams L2->reg, 32 cols/chunk, 2-deep named double buffer. No LDS.
__global__ __launch_bounds__(256, 2)
void sim_kernel(const unsigned short* __restrict__ zn, float* __restrict__ part) {
  const int w    = threadIdx.x >> 6;
  const int lane = threadIdx.x & 63;
  const int l15  = lane & 15;
  const int quad = lane >> 4;

  const int cg    = blockIdx.x & 15;
  const int strip = (blockIdx.x >> 4) * 4 + w;       // 0..255
  const int row_base = strip * 32;
  const int col0     = cg * CGSZ;

  // A fragments: A[m=l15][k=quad*8+kf*32+j], 2 mi-tiles x 4 k-frags.
  bf16x8 a[2][4];
  const unsigned short* abase = zn + (size_t)(row_base + l15) * DDIM + quad * 8;
  #pragma unroll
  for (int mi = 0; mi < 2; ++mi)
    #pragma unroll
    for (int kf = 0; kf < 4; ++kf)
      a[mi][kf] = *(const bf16x8*)(abase + mi * 16 * DDIM + kf * 32);

  float rs[2][4];
  #pragma unroll
  for (int mi = 0; mi < 2; ++mi)
    #pragma unroll
    for (int r = 0; r < 4; ++r) rs[mi][r] = 0.0f;

  // B fragment base: same lane pattern as A (sim = zn * zn^T).
  const unsigned short* bbase = zn + (size_t)(col0 + l15) * DDIM + quad * 8;

#define LOADB(B, CH)                                                           \
  {                                                                            \
    const unsigned short* bp = bbase + (size_t)(CH) * 32 * DDIM;               \
    _Pragma("unroll")                                                          \
    for (int kf = 0; kf < 4; ++kf) {                                           \
      B[0][kf] = *(const bf16x8*)(bp + kf * 32);                               \
      B[1][kf] = *(const bf16x8*)(bp + 16 * DDIM + kf * 32);                   \
    }                                                                          \
  }

#define COMPB(B)                                                               \
  {                                                                            \
    _Pragma("unroll")                                                          \
    for (int ni = 0; ni < 2; ++ni) {                                           \
      f32x4 z = {0.0f, 0.0f, 0.0f, 0.0f};                                      \
      f32x4 acc0 = __builtin_amdgcn_mfma_f32_16x16x32_bf16(a[0][0], B[ni][0], z, 0, 0, 0); \
      f32x4 acc1 = __builtin_amdgcn_mfma_f32_16x16x32_bf16(a[1][0], B[ni][0], z, 0, 0, 0); \
      _Pragma("unroll")                                                        \
      for (int kf = 1; kf < 4; ++kf) {                                         \
        acc0 = __builtin_amdgcn_mfma_f32_16x16x32_bf16(a[0][kf], B[ni][kf], acc0, 0, 0, 0); \
        acc1 = __builtin_amdgcn_mfma_f32_16x16x32_bf16(a[1][kf], B[ni][kf], acc1, 0, 0, 0); \
      }                                                                        \
      _Pragma("unroll")                                                        \
      for (int r = 0; r < 4; ++r) {                                            \
        rs[0][r] += __builtin_amdgcn_exp2f(acc0[r]);                           \
        rs[1][r] += __builtin_amdgcn_exp2f(acc1[r]);                           \
      }                                                                        \
    }                                                                          \
  }

  bf16x8 bA[2][4], bB[2][4];
  LOADB(bA, 0)
  #pragma unroll 1
  for (int ch = 0; ch < NCHUNK; ch += 2) {
    LOADB(bB, ch + 1)                   // issue next chunk's loads
    COMPB(bA)                           // compute current (loads had 2 COMPs)
    if (ch + 2 < NCHUNK) LOADB(bA, ch + 2)
    COMPB(bB)
  }
#undef LOADB
#undef COMPB

  // Row reduce across the 16 cols each l15 covers. C/D layout: col=l15,
  // row=quad*4+reg. Plain store to disjoint slot cg.
  #pragma unroll
  for (int mi = 0; mi < 2; ++mi)
    #pragma unroll
    for (int r = 0; r < 4; ++r) {
      float v = rs[mi][r];
      v += __shfl_xor(v, 1);
      v += __shfl_xor(v, 2);
      v += __shfl_xor(v, 4);
      v += __shfl_xor(v, 8);
      if (l15 == 0)
        part[(size_t)cg * NROWS + row_base + mi * 16 + quad * 4 + r] = v;
    }
}

// ---- Kernel 3: sum 16 slots per row, logs + mean -------------------------
__global__ void finalize_kernel(const float* __restrict__ part,
                                const float* __restrict__ pos,
                                float* __restrict__ out) {
  __shared__ float red[4];
  int r = blockIdx.x * 256 + threadIdx.x;            // grid 32 x 256 = 8192 rows
  float s = 0.0f;
  #pragma unroll
  for (int k = 0; k < NCG; ++k) s += part[(size_t)k * NROWS + r];
  // per row: logsumexp(logits) - logits[0] = log(S - e^2) - ln2 * pos
  float v = logf(s - EXPDIAG) - LN2 * pos[r & (BHALF - 1)];
  #pragma unroll
  for (int off = 1; off < 64; off <<= 1) v += __shfl_xor(v, off);
  int wave = threadIdx.x >> 6, lane = threadIdx.x & 63;
  if (lane == 0) red[wave] = v;
  __syncthreads();
  if (threadIdx.x == 0)
    atomicAdd(out, (red[0] + red[1] + red[2] + red[3]) * (1.0f / 8192.0f));
}

extern "C" void kernel_launch(void* const* d_in, const int* in_sizes, int n_in,
                              void* d_out, int out_size, void* d_ws, size_t ws_size,
                              hipStream_t stream) {
  const float* zi = (const float*)d_in[0];
  const float* zj = (const float*)d_in[1];
  char* ws = (char*)d_ws;
  unsigned short* zn = (unsigned short*)ws;                       // 2 MB
  float* part = (float*)(ws + (size_t)NROWS * DDIM * 2);          // 512 KB (16x8192)
  float* pos  = (float*)(ws + (size_t)NROWS * DDIM * 2
                            + (size_t)NCG * NROWS * 4);           // 16 KB
  float* out = (float*)d_out;

  norm_kernel<<<2048, 256, 0, stream>>>(zi, zj, zn, pos, out);
  sim_kernel<<<1024, 256, 0, stream>>>(zn, part);
  finalize_kernel<<<32, 256, 0, stream>>>(part, pos, out);
}